// Round 1
// baseline (523.944 us; speedup 1.0000x reference)
//
#include <hip/hip_runtime.h>
#include <math.h>

// ECE (signed variant) == (sum(conf) - sum(acc)) / N  -- binning cancels out.
// Row layout: [N=1e6, C=100] fp32. 4 threads per row, float4 loads.

#define N_ROWS 1000000
#define N_COLS 100
#define BLOCK 256
#define ROWS_PER_BLOCK (BLOCK / 4)          // 64 rows per block
#define N_BLOCKS (N_ROWS / ROWS_PER_BLOCK)  // 15625, exact

__global__ __launch_bounds__(BLOCK) void ece_main(
    const float* __restrict__ logits,
    const int* __restrict__ labels,
    double* __restrict__ partials)
{
    const int t   = threadIdx.x;
    const int gid = blockIdx.x * BLOCK + t;
    const int row = gid >> 2;   // 4 threads per row
    const int q   = gid & 3;

    const float4* rowp = reinterpret_cast<const float4*>(logits + (size_t)row * N_COLS);

    // Per-thread max/argmax over its strided float4s (visited in increasing
    // column order, so strict '>' preserves first-occurrence semantics).
    float vmax = -INFINITY;
    int   imax = 0;
#pragma unroll
    for (int k = 0; k < 6; ++k) {
        const int i4 = q + 4 * k;        // float4 index 0..23
        const float4 v = rowp[i4];
        const int c = i4 * 4;
        if (v.x > vmax) { vmax = v.x; imax = c;     }
        if (v.y > vmax) { vmax = v.y; imax = c + 1; }
        if (v.z > vmax) { vmax = v.z; imax = c + 2; }
        if (v.w > vmax) { vmax = v.w; imax = c + 3; }
    }
    if (q == 0) {                        // tail float4 (cols 96..99)
        const float4 v = rowp[24];
        if (v.x > vmax) { vmax = v.x; imax = 96; }
        if (v.y > vmax) { vmax = v.y; imax = 97; }
        if (v.z > vmax) { vmax = v.z; imax = 98; }
        if (v.w > vmax) { vmax = v.w; imax = 99; }
    }

    // Quad butterfly reduce (width 4); tie -> smaller column index (jnp.argmax).
#pragma unroll
    for (int m = 1; m <= 2; m <<= 1) {
        const float vo = __shfl_xor(vmax, m, 4);
        const int   io = __shfl_xor(imax, m, 4);
        if (vo > vmax || (vo == vmax && io < imax)) { vmax = vo; imax = io; }
    }

    double s = 0.0;
    if (q == 0) {
        const float conf = 1.0f / (1.0f + expf(-vmax));   // sigmoid(max logit)
        const float acc  = (imax == labels[row]) ? 1.0f : 0.0f;
        s = (double)conf - (double)acc;
    }

    // Wave (64-lane) reduction, then per-block sum via LDS.
#pragma unroll
    for (int off = 32; off > 0; off >>= 1) s += __shfl_down(s, off, 64);

    __shared__ double wsum[BLOCK / 64];
    if ((t & 63) == 0) wsum[t >> 6] = s;
    __syncthreads();
    if (t == 0) {
        double b = 0.0;
#pragma unroll
        for (int w = 0; w < BLOCK / 64; ++w) b += wsum[w];
        partials[blockIdx.x] = b;
    }
}

__global__ __launch_bounds__(BLOCK) void ece_finalize(
    const double* __restrict__ partials, int nb, float* __restrict__ out)
{
    double s = 0.0;
    for (int i = threadIdx.x; i < nb; i += BLOCK) s += partials[i];
#pragma unroll
    for (int off = 32; off > 0; off >>= 1) s += __shfl_down(s, off, 64);

    __shared__ double wsum[BLOCK / 64];
    if ((threadIdx.x & 63) == 0) wsum[threadIdx.x >> 6] = s;
    __syncthreads();
    if (threadIdx.x == 0) {
        double b = 0.0;
#pragma unroll
        for (int w = 0; w < BLOCK / 64; ++w) b += wsum[w];
        out[0] = (float)(b / (double)N_ROWS);
    }
}

extern "C" void kernel_launch(void* const* d_in, const int* in_sizes, int n_in,
                              void* d_out, int out_size, void* d_ws, size_t ws_size,
                              hipStream_t stream)
{
    const float* logits = (const float*)d_in[0];
    const int*   labels = (const int*)d_in[1];
    float*       out    = (float*)d_out;
    double*      partials = (double*)d_ws;   // 15625 * 8 B = 125 KB

    ece_main<<<N_BLOCKS, BLOCK, 0, stream>>>(logits, labels, partials);
    ece_finalize<<<1, BLOCK, 0, stream>>>(partials, N_BLOCKS, out);
}